// Round 1
// baseline (281.409 us; speedup 1.0000x reference)
//
#include <hip/hip_runtime.h>

#define HID 1024
#define NBATCH 4
#define SEQ 2048
#define BS 8192  // NBATCH*SEQ

typedef __attribute__((ext_vector_type(8))) short short8;
typedef __attribute__((ext_vector_type(8))) unsigned short ushort8;
typedef __attribute__((ext_vector_type(4))) float f32x4;

__device__ __forceinline__ float bf2f(unsigned short u) {
  unsigned int x = ((unsigned int)u) << 16;
  return __builtin_bit_cast(float, x);
}
__device__ __forceinline__ unsigned short f2bf(float f) {
  unsigned int x = __builtin_bit_cast(unsigned int, f);
  x = x + 0x7fffu + ((x >> 16) & 1u);
  return (unsigned short)(x >> 16);
}

#define GLOAD16(g, l)                                                          \
  __builtin_amdgcn_global_load_lds(                                            \
      (const __attribute__((address_space(1))) unsigned int*)(g),              \
      (__attribute__((address_space(3))) unsigned int*)(l), 16, 0, 0)

// ---------------- fp32 -> bf16 cast, 8 elems/thread ----------------
__global__ void cast_f32_to_bf16(const float* __restrict__ in,
                                 unsigned short* __restrict__ out, int n) {
  int i = (blockIdx.x * 256 + threadIdx.x) * 8;
  if (i >= n) return;
  f32x4 a = *(const f32x4*)(in + i);
  f32x4 b = *(const f32x4*)(in + i + 4);
  ushort8 o;
  o[0] = f2bf(a[0]); o[1] = f2bf(a[1]); o[2] = f2bf(a[2]); o[3] = f2bf(a[3]);
  o[4] = f2bf(b[0]); o[5] = f2bf(b[1]); o[6] = f2bf(b[2]); o[7] = f2bf(b[3]);
  *(ushort8*)(out + i) = o;
}

// ---------------- NT GEMM: C[m,n] = alpha * sum_k A[m,k]*B[n,k] (+bias) ----
// m97 structure: 128x128 tile, BK=32, 4 waves (2x2 of 64x64), 16x16x32 MFMA,
// global_load_lds width=16 staging, 2 barriers per K-step.
// BIAS_MODE: 0 = none, 1 = bias[col], 2 = bias[row]. OUT_BF16: output dtype.
template <int OUT_BF16, int BIAS_MODE>
__global__ __launch_bounds__(256) void gemm_nt(
    const unsigned short* __restrict__ A, const unsigned short* __restrict__ B,
    void* __restrict__ Cv, const float* __restrict__ bias, int K, int lda,
    int ldb, int ldc, long long bsA, long long bsB, long long bsC,
    float alpha) {
  __shared__ unsigned short lA[128 * 32];
  __shared__ unsigned short lB[128 * 32];
  const int tid = threadIdx.x;
  const int lane = tid & 63;
  const int wv = tid >> 6;
  const int wr = wv >> 1, wc = wv & 1;
  const int fr = lane & 15, fq = lane >> 4;
  const int z = blockIdx.z;
  const unsigned short* Ag =
      A + (long long)z * bsA + (long long)blockIdx.y * 128 * lda;
  const unsigned short* Bg =
      B + (long long)z * bsB + (long long)blockIdx.x * 128 * ldb;
  const int sr = lane >> 2;        // 16 rows per wave-chunk
  const int sc = (lane & 3) * 8;   // 4 lanes x 8 bf16 = 32-wide K slice

  f32x4 acc[4][4] = {};

  for (int k0 = 0; k0 < K; k0 += 32) {
#pragma unroll
    for (int c = 0; c < 2; ++c) {
      const int rt = (c * 4 + wv) * 16 + sr;
      // LDS dest is wave-uniform base; HW adds lane*16B (linear layout).
      GLOAD16(Ag + (long long)rt * lda + k0 + sc, &lA[(c * 4 + wv) * 512]);
      GLOAD16(Bg + (long long)rt * ldb + k0 + sc, &lB[(c * 4 + wv) * 512]);
    }
    __syncthreads();
    short8 av[4], bv_[4];
#pragma unroll
    for (int m = 0; m < 4; ++m)
      av[m] = *(const short8*)&lA[(wr * 64 + m * 16 + fr) * 32 + fq * 8];
#pragma unroll
    for (int n = 0; n < 4; ++n)
      bv_[n] = *(const short8*)&lB[(wc * 64 + n * 16 + fr) * 32 + fq * 8];
#pragma unroll
    for (int m = 0; m < 4; ++m)
#pragma unroll
      for (int n = 0; n < 4; ++n)
        acc[m][n] = __builtin_amdgcn_mfma_f32_16x16x32_bf16(av[m], bv_[n],
                                                            acc[m][n], 0, 0, 0);
    __syncthreads();
  }

  // Epilogue. C/D layout: col = lane&15, row = (lane>>4)*4 + j.
  const long long cbase = (long long)z * bsC;
  const int rowBase = blockIdx.y * 128 + wr * 64;
  const int colBase = blockIdx.x * 128 + wc * 64;
#pragma unroll
  for (int m = 0; m < 4; ++m) {
#pragma unroll
    for (int n = 0; n < 4; ++n) {
      const int col = colBase + n * 16 + fr;
      const float bc = (BIAS_MODE == 1) ? bias[col] : 0.0f;
#pragma unroll
      for (int j = 0; j < 4; ++j) {
        const int row = rowBase + m * 16 + fq * 4 + j;
        float val = acc[m][n][j] * alpha + bc;
        if (BIAS_MODE == 2) val += bias[row];
        const long long idx = cbase + (long long)row * ldc + col;
        if (OUT_BF16)
          ((unsigned short*)Cv)[idx] = f2bf(val);
        else
          ((float*)Cv)[idx] = val;
      }
    }
  }
}

// ---------------- in-place row softmax over 2048 bf16 ----------------
__global__ __launch_bounds__(256) void softmax_inplace(
    unsigned short* __restrict__ P) {
  __shared__ float red[8];
  unsigned short* p = P + (long long)blockIdx.x * 2048;
  const int tid = threadIdx.x;
  const int lane = tid & 63, w = tid >> 6;
  ushort8 v = *(const ushort8*)(p + tid * 8);
  float f[8];
#pragma unroll
  for (int i = 0; i < 8; ++i) f[i] = bf2f(v[i]);
  float mx = f[0];
#pragma unroll
  for (int i = 1; i < 8; ++i) mx = fmaxf(mx, f[i]);
#pragma unroll
  for (int off = 32; off >= 1; off >>= 1)
    mx = fmaxf(mx, __shfl_xor(mx, off, 64));
  if (lane == 0) red[w] = mx;
  __syncthreads();
  mx = fmaxf(fmaxf(red[0], red[1]), fmaxf(red[2], red[3]));
  float s = 0.f;
#pragma unroll
  for (int i = 0; i < 8; ++i) {
    f[i] = __expf(f[i] - mx);
    s += f[i];
  }
#pragma unroll
  for (int off = 32; off >= 1; off >>= 1) s += __shfl_xor(s, off, 64);
  if (lane == 0) red[4 + w] = s;
  __syncthreads();
  s = (red[4] + red[5]) + (red[6] + red[7]);
  const float inv = 1.0f / s;
  ushort8 o;
#pragma unroll
  for (int i = 0; i < 8; ++i) o[i] = f2bf(f[i] * inv);
  *(ushort8*)(p + tid * 8) = o;
}

extern "C" void kernel_launch(void* const* d_in, const int* in_sizes, int n_in,
                              void* d_out, int out_size, void* d_ws,
                              size_t ws_size, hipStream_t stream) {
  (void)in_sizes; (void)n_in; (void)out_size; (void)ws_size;
  const float* x = (const float*)d_in[0];
  const float* Wq = (const float*)d_in[1];
  const float* bq = (const float*)d_in[2];
  const float* Wk = (const float*)d_in[3];
  const float* bk = (const float*)d_in[4];
  const float* Wv = (const float*)d_in[5];
  const float* bv = (const float*)d_in[6];
  const float* Wo = (const float*)d_in[7];
  const float* bo = (const float*)d_in[8];
  float* out = (float*)d_out;

  char* ws = (char*)d_ws;
  unsigned short* xbf = (unsigned short*)(ws + 0);          // 16 MiB
  unsigned short* wqbf = (unsigned short*)(ws + 16777216);  // 2 MiB
  unsigned short* wkbf = (unsigned short*)(ws + 18874368);
  unsigned short* wvbf = (unsigned short*)(ws + 20971520);
  unsigned short* wobf = (unsigned short*)(ws + 23068672);
  unsigned short* Qb = (unsigned short*)(ws + 25165824);    // 16 MiB
  unsigned short* Kb = (unsigned short*)(ws + 41943040);    // 16 MiB
  unsigned short* Vt = (unsigned short*)(ws + 58720256);    // 16 MiB [H][BS]
  unsigned short* ctx = (unsigned short*)(ws + 75497472);   // 16 MiB
  unsigned short* P = (unsigned short*)(ws + 92274688);     // 32 MiB
  // total ws use: 125,829,120 bytes

  // casts
  cast_f32_to_bf16<<<4096, 256, 0, stream>>>(x, xbf, BS * HID);
  cast_f32_to_bf16<<<512, 256, 0, stream>>>(Wq, wqbf, HID * HID);
  cast_f32_to_bf16<<<512, 256, 0, stream>>>(Wk, wkbf, HID * HID);
  cast_f32_to_bf16<<<512, 256, 0, stream>>>(Wv, wvbf, HID * HID);
  cast_f32_to_bf16<<<512, 256, 0, stream>>>(Wo, wobf, HID * HID);

  // Q = x @ Wq^T + bq : [8192,1024], NT, bias per-col
  gemm_nt<1, 1><<<dim3(8, 64, 1), 256, 0, stream>>>(
      xbf, wqbf, Qb, bq, HID, HID, HID, HID, 0, 0, 0, 1.0f);
  // K = x @ Wk^T + bk
  gemm_nt<1, 1><<<dim3(8, 64, 1), 256, 0, stream>>>(
      xbf, wkbf, Kb, bk, HID, HID, HID, HID, 0, 0, 0, 1.0f);
  // Vt = Wv @ x^T + bv : [1024, 8192] (V transposed for free), bias per-row
  gemm_nt<1, 2><<<dim3(64, 8, 1), 256, 0, stream>>>(
      wvbf, xbf, Vt, bv, HID, HID, HID, BS, 0, 0, 0, 1.0f);
  // P = Q @ K^T / sqrt(H) per batch : [4][2048][2048] bf16
  gemm_nt<1, 0><<<dim3(16, 16, NBATCH), 256, 0, stream>>>(
      Qb, Kb, P, nullptr, HID, HID, HID, SEQ, (long long)SEQ * HID,
      (long long)SEQ * HID, (long long)SEQ * SEQ, 0.03125f);
  // softmax rows, in place
  softmax_inplace<<<BS, 256, 0, stream>>>(P);
  // ctx = P @ Vt(+z*2048)^T : [2048,1024] per batch
  gemm_nt<1, 0><<<dim3(8, 16, NBATCH), 256, 0, stream>>>(
      P, Vt, ctx, nullptr, SEQ, SEQ, BS, HID, (long long)SEQ * SEQ,
      (long long)SEQ, (long long)SEQ * HID, 1.0f);
  // out = ctx @ Wo^T + bo : fp32 output
  gemm_nt<0, 1><<<dim3(8, 64, 1), 256, 0, stream>>>(
      ctx, wobf, out, bo, HID, HID, HID, HID, 0, 0, 0, 1.0f);
}

// Round 2
// 240.034 us; speedup vs baseline: 1.1724x; 1.1724x over previous
//
#include <hip/hip_runtime.h>

#define HID 1024
#define SEQ 2048
#define NB 4
#define BS 8192  // NB*SEQ

typedef __attribute__((ext_vector_type(8))) short short8;
typedef __attribute__((ext_vector_type(8))) unsigned short ushort8;
typedef __attribute__((ext_vector_type(4))) float f32x4;

__device__ __forceinline__ float bf2f(unsigned short u) {
  unsigned int x = ((unsigned int)u) << 16;
  return __builtin_bit_cast(float, x);
}
__device__ __forceinline__ unsigned short f2bf(float f) {
  unsigned int x = __builtin_bit_cast(unsigned int, f);
  x = x + 0x7fffu + ((x >> 16) & 1u);
  return (unsigned short)(x >> 16);
}

#define GLOAD16(g, l)                                                          \
  __builtin_amdgcn_global_load_lds(                                            \
      (const __attribute__((address_space(1))) unsigned int*)(g),              \
      (__attribute__((address_space(3))) unsigned int*)(l), 16, 0, 0)

// ---------------- fp32 -> bf16 cast, 8 elems/thread ----------------
__global__ void cast_f32_to_bf16(const float* __restrict__ in,
                                 unsigned short* __restrict__ out, int n) {
  int i = (blockIdx.x * 256 + threadIdx.x) * 8;
  if (i >= n) return;
  f32x4 a = *(const f32x4*)(in + i);
  f32x4 b = *(const f32x4*)(in + i + 4);
  ushort8 o;
  o[0] = f2bf(a[0]); o[1] = f2bf(a[1]); o[2] = f2bf(a[2]); o[3] = f2bf(a[3]);
  o[4] = f2bf(b[0]); o[5] = f2bf(b[1]); o[6] = f2bf(b[2]); o[7] = f2bf(b[3]);
  *(ushort8*)(out + i) = o;
}

// ======================= 256x BN 8-phase NT GEMM ==========================
// C[m,n] = alpha * sum_k A[m,k]*B[n,k] (+bias). BM=256, BK=64, 512 thr.
// BIAS_MODE: 0 none, 1 bias[col], 2 bias[row], 3 col<1024?bias:bias2.
template <int BN, int OUT_F32, int BIAS_MODE>
__global__ __launch_bounds__(512, 2) void gemm8p(
    const unsigned short* __restrict__ A, const unsigned short* __restrict__ B,
    void* __restrict__ Cv, const float* __restrict__ bias,
    const float* __restrict__ bias2, int K, int lda, int ldb, int ldc,
    long long bsA, long long bsB, long long bsC, float alpha) {
  static_assert(BN == 256 || BN == 128, "BN");
  constexpr int WMW = (BN == 256) ? 2 : 4;  // waves along M
  constexpr int WNW = 8 / WMW;              // waves along N
  constexpr int MF = 8 / WMW;               // M frags per quadrant-phase
  constexpr int NF = 2;                     // N frags per quadrant-phase
  constexpr int NBH = BN / 2;               // B half-tile rows
  constexpr int GB = (BN == 256) ? 2 : 1;   // gloads per B half-tile
  constexpr int VMS = 2 + GB;               // steady-state vmcnt
  constexpr int BSLOT = NBH * 64;           // ushorts per B half-slot

  __shared__ unsigned short ldsA[4 * 8192];   // [buf*2+half][128x64]
  __shared__ unsigned short ldsB[4 * BSLOT];  // [buf*2+half][NBH x 64]

  const int tid = threadIdx.x;
  const int lane = tid & 63, wid = tid >> 6;
  const int fr = lane & 15, fq = lane >> 4;
  const int wm = wid / WNW, wn = wid % WNW;
  const int bx = blockIdx.x, by = blockIdx.y, bz = blockIdx.z;
  const unsigned short* Ag = A + bz * bsA + (long long)by * 256 * lda;
  const unsigned short* Bg = B + bz * bsB + (long long)bx * BN * ldb;
  const int NT = K >> 6;

  // Staging geometry: LDS write is linear (base + lane*16B); apply the LDS
  // XOR-swizzle (bits[6:4] ^= bits[10:8]) to the GLOBAL source instead
  // (involution; both sides must match - rule 21).
  const int La0 = wid * 1024 + lane * 16;
  const int La1 = 8192 + La0;
  const int Pa0 = La0 ^ ((La0 >> 4) & 0x70);
  const int Pa1 = La1 ^ ((La1 >> 4) & 0x70);
  const int aR0 = Pa0 >> 7, aC0 = (Pa0 & 127) >> 1;
  const int aR1 = Pa1 >> 7, aC1 = (Pa1 & 127) >> 1;

  auto stageA = [&](int tile, int h) {
    if (tile >= NT) return;
    unsigned short* d = &ldsA[(((tile & 1) << 1) | h) * 8192 + wid * 512];
    GLOAD16(Ag + (long long)(h * 128 + aR0) * lda + tile * 64 + aC0, d);
    GLOAD16(Ag + (long long)(h * 128 + aR1) * lda + tile * 64 + aC1, d + 4096);
  };
  auto stageB = [&](int tile, int h) {
    if (tile >= NT) return;
    unsigned short* d = &ldsB[(((tile & 1) << 1) | h) * BSLOT + wid * 512];
    GLOAD16(Bg + (long long)(h * NBH + aR0) * ldb + tile * 64 + aC0, d);
    if (GB == 2)
      GLOAD16(Bg + (long long)(h * NBH + aR1) * ldb + tile * 64 + aC1, d + 4096);
  };

  // Fragment ds_read offsets (swizzled), ushort units.
  int offA[MF][2], offB[NF][2];
#pragma unroll
  for (int i = 0; i < MF; ++i)
#pragma unroll
    for (int s = 0; s < 2; ++s) {
      int b = (wm * (128 / WMW) + i * 16 + fr) * 128 + s * 64 + fq * 16;
      offA[i][s] = (b ^ ((b >> 4) & 0x70)) >> 1;
    }
#pragma unroll
  for (int n = 0; n < NF; ++n)
#pragma unroll
    for (int s = 0; s < 2; ++s) {
      int b = (wn * 32 + n * 16 + fr) * 128 + s * 64 + fq * 16;
      offB[n][s] = (b ^ ((b >> 4) & 0x70)) >> 1;
    }

  f32x4 acc[2][2][MF][NF] = {};

  // Prologue: tile0 fully + tile1 h0s; leave tile1-h0 loads in flight.
  stageA(0, 0); stageB(0, 0); stageA(0, 1); stageB(0, 1);
  stageA(1, 0); stageB(1, 0);
  asm volatile("s_waitcnt vmcnt(%0)" ::"i"(VMS) : "memory");
  __builtin_amdgcn_s_barrier();

  for (int kt = 0; kt < NT; kt += 2) {
#pragma unroll
    for (int t2 = 0; t2 < 2; ++t2) {
      const int buf = (kt + t2) & 1;
#pragma unroll
      for (int ph = 0; ph < 4; ++ph) {
        const int mh = ph >> 1, nh = ph & 1;
        const int p = t2 * 4 + ph;
        short8 av[MF][2], bw[NF][2];
        const unsigned short* pa = &ldsA[((buf << 1) | mh) * 8192];
        const unsigned short* pb = &ldsB[((buf << 1) | nh) * BSLOT];
#pragma unroll
        for (int i = 0; i < MF; ++i)
#pragma unroll
          for (int s = 0; s < 2; ++s)
            av[i][s] = *(const short8*)(pa + offA[i][s]);
#pragma unroll
        for (int n = 0; n < NF; ++n)
#pragma unroll
          for (int s = 0; s < 2; ++s)
            bw[n][s] = *(const short8*)(pb + offB[n][s]);
        // Staging schedule: each slot's overwrite issues one phase after the
        // last read of its previous occupant (WAR safe via the barriers).
        if (p == 0) stageA(kt + 1, 1);
        else if (p == 1) stageB(kt + 1, 1);
        else if (p == 2) stageA(kt + 2, 0);
        else if (p == 3) stageB(kt + 2, 0);
        else if (p == 4) stageA(kt + 2, 1);
        else if (p == 5) stageB(kt + 2, 1);
        else if (p == 6) stageA(kt + 3, 0);
        else stageB(kt + 3, 0);
        __builtin_amdgcn_s_barrier();
        __builtin_amdgcn_s_setprio(1);
#pragma unroll
        for (int i = 0; i < MF; ++i)
#pragma unroll
          for (int n = 0; n < NF; ++n)
#pragma unroll
            for (int s = 0; s < 2; ++s)
              acc[mh][nh][i][n] = __builtin_amdgcn_mfma_f32_16x16x32_bf16(
                  av[i][s], bw[n][s], acc[mh][nh][i][n], 0, 0, 0);
        __builtin_amdgcn_s_setprio(0);
        if (p == 3) {
          if (kt + 2 < NT)
            asm volatile("s_waitcnt vmcnt(%0)" ::"i"(VMS) : "memory");
          else
            asm volatile("s_waitcnt vmcnt(0)" ::: "memory");
        }
        if (p == 7) {
          if (kt + 3 < NT)
            asm volatile("s_waitcnt vmcnt(%0)" ::"i"(VMS) : "memory");
          else
            asm volatile("s_waitcnt vmcnt(0)" ::: "memory");
        }
        __builtin_amdgcn_s_barrier();
      }
    }
  }

  // Epilogue. C/D frag layout: col = 16*frag + fr, row = fq*4 + j.
  const long long cb0 = (long long)bz * bsC;
#pragma unroll
  for (int mh = 0; mh < 2; ++mh)
#pragma unroll
    for (int nh = 0; nh < 2; ++nh)
#pragma unroll
      for (int i = 0; i < MF; ++i)
#pragma unroll
        for (int n = 0; n < NF; ++n) {
          const int col = bx * BN + nh * NBH + wn * 32 + n * 16 + fr;
          float cbias = 0.f;
          if (BIAS_MODE == 1) cbias = bias[col];
          if (BIAS_MODE == 3)
            cbias = (col < 1024) ? bias[col] : bias2[col - 1024];
#pragma unroll
          for (int j = 0; j < 4; ++j) {
            const int row =
                by * 256 + mh * 128 + wm * (128 / WMW) + i * 16 + fq * 4 + j;
            float v = acc[mh][nh][i][n][j] * alpha + cbias;
            if (BIAS_MODE == 2) v += bias[row];
            const long long idx = cb0 + (long long)row * ldc + col;
            if (OUT_F32)
              ((float*)Cv)[idx] = v;
            else
              ((unsigned short*)Cv)[idx] = f2bf(v);
          }
        }
}

// ---------------- in-place row softmax over 2048 bf16 ----------------
__global__ __launch_bounds__(256) void softmax_inplace(
    unsigned short* __restrict__ P) {
  __shared__ float red[8];
  unsigned short* p = P + (long long)blockIdx.x * 2048;
  const int tid = threadIdx.x;
  const int lane = tid & 63, w = tid >> 6;
  ushort8 v = *(const ushort8*)(p + tid * 8);
  float f[8];
#pragma unroll
  for (int i = 0; i < 8; ++i) f[i] = bf2f(v[i]);
  float mx = f[0];
#pragma unroll
  for (int i = 1; i < 8; ++i) mx = fmaxf(mx, f[i]);
#pragma unroll
  for (int off = 32; off >= 1; off >>= 1)
    mx = fmaxf(mx, __shfl_xor(mx, off, 64));
  if (lane == 0) red[w] = mx;
  __syncthreads();
  mx = fmaxf(fmaxf(red[0], red[1]), fmaxf(red[2], red[3]));
  float s = 0.f;
#pragma unroll
  for (int i = 0; i < 8; ++i) {
    f[i] = __expf(f[i] - mx);
    s += f[i];
  }
#pragma unroll
  for (int off = 32; off >= 1; off >>= 1) s += __shfl_xor(s, off, 64);
  if (lane == 0) red[4 + w] = s;
  __syncthreads();
  s = (red[4] + red[5]) + (red[6] + red[7]);
  const float inv = 1.0f / s;
  ushort8 o;
#pragma unroll
  for (int i = 0; i < 8; ++i) o[i] = f2bf(f[i] * inv);
  *(ushort8*)(p + tid * 8) = o;
}

extern "C" void kernel_launch(void* const* d_in, const int* in_sizes, int n_in,
                              void* d_out, int out_size, void* d_ws,
                              size_t ws_size, hipStream_t stream) {
  (void)in_sizes; (void)n_in; (void)out_size; (void)ws_size;
  const float* x = (const float*)d_in[0];
  const float* Wq = (const float*)d_in[1];
  const float* bq = (const float*)d_in[2];
  const float* Wk = (const float*)d_in[3];
  const float* bk = (const float*)d_in[4];
  const float* Wv = (const float*)d_in[5];
  const float* bv = (const float*)d_in[6];
  const float* Wo = (const float*)d_in[7];
  const float* bo = (const float*)d_in[8];
  float* out = (float*)d_out;

  char* ws = (char*)d_ws;
  unsigned short* xbf  = (unsigned short*)(ws + 0);          // 16 MiB
  unsigned short* wqk  = (unsigned short*)(ws + 16777216);   // 4 MiB [2048][1024]
  unsigned short* wvbf = (unsigned short*)(ws + 20971520);   // 2 MiB
  unsigned short* wobf = (unsigned short*)(ws + 23068672);   // 2 MiB
  unsigned short* QKb  = (unsigned short*)(ws + 25165824);   // 32 MiB [8192][2048]
  unsigned short* Vt   = (unsigned short*)(ws + 58720256);   // 16 MiB [1024][8192]
  unsigned short* ctxb = (unsigned short*)(ws + 75497472);   // 16 MiB [8192][1024]
  unsigned short* P    = (unsigned short*)(ws + 92274688);   // 32 MiB [4][2048][2048]
  // total 125,829,120 bytes (same footprint as round 1)

  // casts
  cast_f32_to_bf16<<<4096, 256, 0, stream>>>(x, xbf, BS * HID);
  cast_f32_to_bf16<<<512, 256, 0, stream>>>(Wq, wqk, HID * HID);
  cast_f32_to_bf16<<<512, 256, 0, stream>>>(Wk, wqk + HID * HID, HID * HID);
  cast_f32_to_bf16<<<512, 256, 0, stream>>>(Wv, wvbf, HID * HID);
  cast_f32_to_bf16<<<512, 256, 0, stream>>>(Wo, wobf, HID * HID);

  // [Q|K] = x @ [Wq;Wk]^T + [bq;bk] : [8192,2048]
  gemm8p<256, 0, 3><<<dim3(8, 32, 1), 512, 0, stream>>>(
      xbf, wqk, QKb, bq, bk, HID, HID, HID, 2048, 0, 0, 0, 1.0f);
  // Vt = Wv @ x^T + bv (row-bias) : [1024, 8192]
  gemm8p<128, 0, 2><<<dim3(64, 4, 1), 512, 0, stream>>>(
      wvbf, xbf, Vt, bv, nullptr, HID, HID, HID, BS, 0, 0, 0, 1.0f);
  // P = Q @ K^T / 32 per batch : [4][2048][2048]
  gemm8p<256, 0, 0><<<dim3(8, 8, NB), 512, 0, stream>>>(
      QKb, QKb + 1024, P, nullptr, nullptr, HID, 2048, 2048, SEQ,
      (long long)SEQ * 2048, (long long)SEQ * 2048, (long long)SEQ * SEQ,
      0.03125f);
  // softmax rows in place
  softmax_inplace<<<BS, 256, 0, stream>>>(P);
  // ctx = P @ Vt^T per batch (k-window shift via bsB) : [8192,1024]
  gemm8p<128, 0, 0><<<dim3(8, 8, NB), 512, 0, stream>>>(
      P, Vt, ctxb, nullptr, nullptr, SEQ, SEQ, BS, HID,
      (long long)SEQ * SEQ, (long long)SEQ, (long long)SEQ * HID, 1.0f);
  // out = ctx @ Wo^T + bo : fp32
  gemm8p<128, 1, 1><<<dim3(8, 32, 1), 512, 0, stream>>>(
      ctxb, wobf, out, bo, nullptr, HID, HID, HID, HID, 0, 0, 0, 1.0f);
}